// Round 1
// baseline (635.410 us; speedup 1.0000x reference)
//
#include <hip/hip_runtime.h>
#include <stdint.h>

#define NNODES 50000
#define NEDGES 800000
#define DIM 128
#define IN1 512
#define IN2 384

typedef __attribute__((ext_vector_type(8))) short bf16x8;
typedef __attribute__((ext_vector_type(8))) unsigned short u16x8;
typedef __attribute__((ext_vector_type(4))) float f32x4;

__device__ __forceinline__ unsigned short f2bf(float f) {
  union { float f; uint32_t u; } v; v.f = f;
  return (unsigned short)((v.u + 0x7FFFu + ((v.u >> 16) & 1u)) >> 16);
}

// load 8 consecutive floats from p, convert to bf16, store 16B into LDS at ushort index sidx
__device__ __forceinline__ void cvt8(const float* __restrict__ p, unsigned short* dst, int sidx) {
  float4 f0 = *(const float4*)(p);
  float4 f1 = *(const float4*)(p + 4);
  u16x8 o;
  o[0] = f2bf(f0.x); o[1] = f2bf(f0.y); o[2] = f2bf(f0.z); o[3] = f2bf(f0.w);
  o[4] = f2bf(f1.x); o[5] = f2bf(f1.y); o[6] = f2bf(f1.z); o[7] = f2bf(f1.w);
  *(u16x8*)(dst + sidx) = o;
}

// ---------------- edge kernel: messages = relu([x[dst]|x[src]|ea|u[batch[dst]]] @ W1^T + b1)
//                  scatter-add into agg[dst] ----------------
__global__ __launch_bounds__(256, 2) void edge_kernel(
    const float* __restrict__ x, const int* __restrict__ srcI, const int* __restrict__ dstI,
    const float* __restrict__ ea, const float* __restrict__ u, const int* __restrict__ batch,
    const float* __restrict__ W1, const float* __restrict__ b1,
    float* __restrict__ agg)
{
  __shared__ __align__(16) unsigned short As[128 * 128];
  __shared__ __align__(16) unsigned short Bs[128 * 128];

  const int t  = threadIdx.x;
  const int l  = t & 63;
  const int w  = t >> 6;
  const int wm = w >> 1, wn = w & 1;
  const int e0 = blockIdx.x * 128;
  const int r  = t >> 1, h = t & 1;      // staging: row r (0..127), half h

  f32x4 acc[4][4] = {};

#pragma unroll
  for (int c = 0; c < 4; ++c) {
    __syncthreads();
    // ---- stage A chunk (128 edges x 128 feats, fp32 -> bf16, swizzled) ----
    const float* rowp;
    if (c == 0)      rowp = x  + (size_t)dstI[e0 + r] * DIM;
    else if (c == 1) rowp = x  + (size_t)srcI[e0 + r] * DIM;
    else if (c == 2) rowp = ea + (size_t)(e0 + r) * DIM;
    else             rowp = u  + (size_t)batch[dstI[e0 + r]] * DIM;
    rowp += h * 64;
    const int swz = (r & 7) << 3;
#pragma unroll
    for (int i = 0; i < 8; ++i) {
      int sidx = (r * 128 + h * 64 + i * 8) ^ swz;
      cvt8(rowp + i * 8, As, sidx);
    }
    // ---- stage B chunk: Bs[n][k_local] = bf16(W1[n][c*128 + k_local]) ----
    {
      const float* bp = W1 + (size_t)r * IN1 + c * 128 + h * 64;
#pragma unroll
      for (int i = 0; i < 8; ++i) {
        int sidx = (r * 128 + h * 64 + i * 8) ^ swz;
        cvt8(bp + i * 8, Bs, sidx);
      }
    }
    __syncthreads();
    // ---- compute: 4 k-steps of K=32 ----
#pragma unroll
    for (int kk = 0; kk < 4; ++kk) {
      bf16x8 a[4], b[4];
#pragma unroll
      for (int mi = 0; mi < 4; ++mi) {
        int row = wm * 64 + mi * 16 + (l & 15);
        int idx = (row * 128 + kk * 32 + (l >> 4) * 8) ^ ((row & 7) << 3);
        a[mi] = *(const bf16x8*)(As + idx);
      }
#pragma unroll
      for (int ni = 0; ni < 4; ++ni) {
        int nrow = wn * 64 + ni * 16 + (l & 15);
        int idx = (nrow * 128 + kk * 32 + (l >> 4) * 8) ^ ((nrow & 7) << 3);
        b[ni] = *(const bf16x8*)(Bs + idx);
      }
#pragma unroll
      for (int mi = 0; mi < 4; ++mi)
#pragma unroll
        for (int ni = 0; ni < 4; ++ni)
          acc[mi][ni] = __builtin_amdgcn_mfma_f32_16x16x32_bf16(a[mi], b[ni], acc[mi][ni], 0, 0, 0);
    }
  }

  // ---- epilogue: bias + relu + atomic scatter to agg[dst] ----
#pragma unroll
  for (int mi = 0; mi < 4; ++mi) {
#pragma unroll
    for (int rr = 0; rr < 4; ++rr) {
      int m = wm * 64 + mi * 16 + (l >> 4) * 4 + rr;
      int d = dstI[e0 + m];
      float* aggrow = agg + (size_t)d * DIM;
#pragma unroll
      for (int ni = 0; ni < 4; ++ni) {
        int col = wn * 64 + ni * 16 + (l & 15);
        float v = acc[mi][ni][rr] + b1[col];
        v = fmaxf(v, 0.0f);
        unsafeAtomicAdd(aggrow + col, v);
      }
    }
  }
}

// ---------------- node kernel: out = relu([x|agg|u[batch]] @ W2^T + b2) ----------------
__global__ __launch_bounds__(256, 2) void node_kernel(
    const float* __restrict__ x, const float* __restrict__ agg, const float* __restrict__ u,
    const int* __restrict__ batch, const float* __restrict__ W2, const float* __restrict__ b2,
    float* __restrict__ out)
{
  __shared__ __align__(16) unsigned short As[128 * 128];
  __shared__ __align__(16) unsigned short Bs[128 * 128];

  const int t  = threadIdx.x;
  const int l  = t & 63;
  const int w  = t >> 6;
  const int wm = w >> 1, wn = w & 1;
  const int n0 = blockIdx.x * 128;
  const int r  = t >> 1, h = t & 1;

  f32x4 acc[4][4] = {};

#pragma unroll
  for (int c = 0; c < 3; ++c) {
    __syncthreads();
    int n = n0 + r; if (n > NNODES - 1) n = NNODES - 1;
    const float* rowp;
    if (c == 0)      rowp = x   + (size_t)n * DIM;
    else if (c == 1) rowp = agg + (size_t)n * DIM;
    else             rowp = u   + (size_t)batch[n] * DIM;
    rowp += h * 64;
    const int swz = (r & 7) << 3;
#pragma unroll
    for (int i = 0; i < 8; ++i) {
      int sidx = (r * 128 + h * 64 + i * 8) ^ swz;
      cvt8(rowp + i * 8, As, sidx);
    }
    {
      const float* bp = W2 + (size_t)r * IN2 + c * 128 + h * 64;
#pragma unroll
      for (int i = 0; i < 8; ++i) {
        int sidx = (r * 128 + h * 64 + i * 8) ^ swz;
        cvt8(bp + i * 8, Bs, sidx);
      }
    }
    __syncthreads();
#pragma unroll
    for (int kk = 0; kk < 4; ++kk) {
      bf16x8 a[4], b[4];
#pragma unroll
      for (int mi = 0; mi < 4; ++mi) {
        int row = wm * 64 + mi * 16 + (l & 15);
        int idx = (row * 128 + kk * 32 + (l >> 4) * 8) ^ ((row & 7) << 3);
        a[mi] = *(const bf16x8*)(As + idx);
      }
#pragma unroll
      for (int ni = 0; ni < 4; ++ni) {
        int nrow = wn * 64 + ni * 16 + (l & 15);
        int idx = (nrow * 128 + kk * 32 + (l >> 4) * 8) ^ ((nrow & 7) << 3);
        b[ni] = *(const bf16x8*)(Bs + idx);
      }
#pragma unroll
      for (int mi = 0; mi < 4; ++mi)
#pragma unroll
        for (int ni = 0; ni < 4; ++ni)
          acc[mi][ni] = __builtin_amdgcn_mfma_f32_16x16x32_bf16(a[mi], b[ni], acc[mi][ni], 0, 0, 0);
    }
  }

#pragma unroll
  for (int mi = 0; mi < 4; ++mi) {
#pragma unroll
    for (int rr = 0; rr < 4; ++rr) {
      int m = wm * 64 + mi * 16 + (l >> 4) * 4 + rr;
      int n = n0 + m;
      if (n < NNODES) {
        float* orow = out + (size_t)n * DIM;
#pragma unroll
        for (int ni = 0; ni < 4; ++ni) {
          int col = wn * 64 + ni * 16 + (l & 15);
          float v = acc[mi][ni][rr] + b2[col];
          orow[col] = fmaxf(v, 0.0f);
        }
      }
    }
  }
}

extern "C" void kernel_launch(void* const* d_in, const int* in_sizes, int n_in,
                              void* d_out, int out_size, void* d_ws, size_t ws_size,
                              hipStream_t stream) {
  const float* x   = (const float*)d_in[0];
  const int* ei    = (const int*)d_in[1];
  const float* ea  = (const float*)d_in[2];
  const float* u   = (const float*)d_in[3];
  const int* batch = (const int*)d_in[4];
  const float* W1  = (const float*)d_in[5];
  const float* b1  = (const float*)d_in[6];
  const float* W2  = (const float*)d_in[7];
  const float* b2  = (const float*)d_in[8];
  float* out = (float*)d_out;

  const int* srcI = ei;
  const int* dstI = ei + NEDGES;

  const size_t agg_bytes = (size_t)NNODES * DIM * sizeof(float);
  // agg lives in workspace; if ws is too small, reuse d_out (safe: node block i
  // reads agg rows [n0,n0+128) and writes out rows [n0,n0+128) only).
  float* agg = (ws_size >= agg_bytes) ? (float*)d_ws : out;

  hipMemsetAsync(agg, 0, agg_bytes, stream);
  edge_kernel<<<NEDGES / 128, 256, 0, stream>>>(x, srcI, dstI, ea, u, batch, W1, b1, agg);
  node_kernel<<<(NNODES + 127) / 128, 256, 0, stream>>>(x, agg, u, batch, W2, b2, out);
}

// Round 2
// 568.395 us; speedup vs baseline: 1.1179x; 1.1179x over previous
//
#include <hip/hip_runtime.h>
#include <stdint.h>

#define NNODES 50000
#define NEDGES 800000
#define DIM 128
#define IN1 512
#define IN2 384

typedef __attribute__((ext_vector_type(8))) short bf16x8;
typedef __attribute__((ext_vector_type(8))) unsigned short u16x8;
typedef __attribute__((ext_vector_type(4))) float f32x4;

__device__ __forceinline__ unsigned short f2bf(float f) {
  union { float f; uint32_t u; } v; v.f = f;
  return (unsigned short)((v.u + 0x7FFFu + ((v.u >> 16) & 1u)) >> 16);
}
__device__ __forceinline__ float bf2f(unsigned short u) {
  union { uint32_t u; float f; } v; v.u = ((uint32_t)u) << 16;
  return v.f;
}

// load 8 consecutive floats, convert to bf16, store 16B into LDS at ushort index sidx
__device__ __forceinline__ void cvt8(const float* __restrict__ p, unsigned short* dst, int sidx) {
  float4 f0 = *(const float4*)(p);
  float4 f1 = *(const float4*)(p + 4);
  u16x8 o;
  o[0] = f2bf(f0.x); o[1] = f2bf(f0.y); o[2] = f2bf(f0.z); o[3] = f2bf(f0.w);
  o[4] = f2bf(f1.x); o[5] = f2bf(f1.y); o[6] = f2bf(f1.z); o[7] = f2bf(f1.w);
  *(u16x8*)(dst + sidx) = o;
}

// 128x128x128 bf16 MFMA macro-tile: 4 waves as 2x2 of 64x64, acc += As @ Bs^T
__device__ __forceinline__ void mfma128(const unsigned short* As, const unsigned short* Bs,
                                        f32x4 acc[4][4], int wm, int wn, int l) {
#pragma unroll
  for (int kk = 0; kk < 4; ++kk) {
    bf16x8 a[4], b[4];
#pragma unroll
    for (int mi = 0; mi < 4; ++mi) {
      int row = wm * 64 + mi * 16 + (l & 15);
      int idx = (row * 128 + kk * 32 + (l >> 4) * 8) ^ ((row & 7) << 3);
      a[mi] = *(const bf16x8*)(As + idx);
    }
#pragma unroll
    for (int ni = 0; ni < 4; ++ni) {
      int nrow = wn * 64 + ni * 16 + (l & 15);
      int idx = (nrow * 128 + kk * 32 + (l >> 4) * 8) ^ ((nrow & 7) << 3);
      b[ni] = *(const bf16x8*)(Bs + idx);
    }
#pragma unroll
    for (int mi = 0; mi < 4; ++mi)
#pragma unroll
      for (int ni = 0; ni < 4; ++ni)
        acc[mi][ni] = __builtin_amdgcn_mfma_f32_16x16x32_bf16(a[mi], b[ni], acc[mi][ni], 0, 0, 0);
  }
}

// ---------------- P0: Ud = u@W1d^T + b1 ; Uc = u@W2c^T + b2 (tiny) ----------------
__global__ void p0_kernel(const float* __restrict__ u,
                          const float* __restrict__ W1, const float* __restrict__ b1,
                          const float* __restrict__ W2, const float* __restrict__ b2,
                          float* __restrict__ Ud, float* __restrict__ Uc) {
  int g = blockIdx.x;          // graph 0..63
  int c = threadIdx.x;         // out col 0..127
  const float* ur = u + (size_t)g * DIM;
  const float* w1 = W1 + (size_t)c * IN1 + 384;   // u segment of W1
  const float* w2 = W2 + (size_t)c * IN2 + 256;   // u segment of W2
  float s1 = b1[c], s2 = b2[c];
  for (int k = 0; k < DIM; ++k) {
    float uv = ur[k];
    s1 += uv * w1[k];
    s2 += uv * w2[k];
  }
  Ud[g * DIM + c] = s1;
  Uc[g * DIM + c] = s2;
}

// ---------------- P1: per-node precompute ----------------
// Xad[n] = bf16( x[n]@W1a^T + Ud[batch[n]] )        (dest-term + u-term + b1)
// Xb [n] = bf16( x[n]@W1b^T )                        (source-term)
// Yx [n] = bf16( x[n]@W2a^T + Uc[batch[n]] )         (node x-term + u-term + b2)
__global__ __launch_bounds__(256, 2) void p1_kernel(
    const float* __restrict__ x, const int* __restrict__ batch,
    const float* __restrict__ W1, const float* __restrict__ W2,
    const float* __restrict__ Ud, const float* __restrict__ Uc,
    unsigned short* __restrict__ Xad, unsigned short* __restrict__ Xb,
    unsigned short* __restrict__ Yx) {
  __shared__ __align__(16) unsigned short As[128 * 128];
  __shared__ __align__(16) unsigned short Bs[128 * 128];
  const int t = threadIdx.x, l = t & 63, w = t >> 6, wm = w >> 1, wn = w & 1;
  const int n0 = blockIdx.x * 128, r = t >> 1, h = t & 1;
  const int swz = (r & 7) << 3;
  {
    int n = n0 + r; if (n >= NNODES) n = NNODES - 1;
    const float* rowp = x + (size_t)n * DIM + h * 64;
#pragma unroll
    for (int i = 0; i < 8; ++i) cvt8(rowp + i * 8, As, (r * 128 + h * 64 + i * 8) ^ swz);
  }
#pragma unroll
  for (int p = 0; p < 3; ++p) {
    __syncthreads();
    const float* bp = (p == 0) ? (W1 + (size_t)r * IN1)
                    : (p == 1) ? (W1 + (size_t)r * IN1 + 128)
                               : (W2 + (size_t)r * IN2);
    bp += h * 64;
#pragma unroll
    for (int i = 0; i < 8; ++i) cvt8(bp + i * 8, Bs, (r * 128 + h * 64 + i * 8) ^ swz);
    __syncthreads();
    f32x4 acc[4][4] = {};
    mfma128(As, Bs, acc, wm, wn, l);
#pragma unroll
    for (int mi = 0; mi < 4; ++mi)
#pragma unroll
      for (int rr = 0; rr < 4; ++rr) {
        int m = wm * 64 + mi * 16 + (l >> 4) * 4 + rr;
        int n = n0 + m;
        if (n < NNODES) {
          int g = batch[n];
#pragma unroll
          for (int ni = 0; ni < 4; ++ni) {
            int col = wn * 64 + ni * 16 + (l & 15);
            float v = acc[mi][ni][rr];
            if (p == 0)      Xad[(size_t)n * DIM + col] = f2bf(v + Ud[g * DIM + col]);
            else if (p == 1) Xb [(size_t)n * DIM + col] = f2bf(v);
            else             Yx [(size_t)n * DIM + col] = f2bf(v + Uc[g * DIM + col]);
          }
        }
      }
  }
}

// ---------------- edge: acc = ea@W1c^T ; msg = relu(acc + Xad[dst] + Xb[src]) ; agg[dst]+=msg ----
__global__ __launch_bounds__(256, 2) void edge_kernel(
    const float* __restrict__ ea, const int* __restrict__ srcI, const int* __restrict__ dstI,
    const float* __restrict__ W1,
    const unsigned short* __restrict__ Xad, const unsigned short* __restrict__ Xb,
    float* __restrict__ agg) {
  __shared__ __align__(16) unsigned short As[128 * 128];
  __shared__ __align__(16) unsigned short Bs[128 * 128];
  const int t = threadIdx.x, l = t & 63, w = t >> 6, wm = w >> 1, wn = w & 1;
  const int e0 = blockIdx.x * 128, r = t >> 1, h = t & 1;
  const int swz = (r & 7) << 3;
  // stage A = ea tile (coalesced stream)
  {
    const float* rowp = ea + (size_t)(e0 + r) * DIM + h * 64;
#pragma unroll
    for (int i = 0; i < 8; ++i) cvt8(rowp + i * 8, As, (r * 128 + h * 64 + i * 8) ^ swz);
  }
  // stage B = W1c (edge_attr segment of W1, cols 256..383) — L2-hot
  {
    const float* bp = W1 + (size_t)r * IN1 + 256 + h * 64;
#pragma unroll
    for (int i = 0; i < 8; ++i) cvt8(bp + i * 8, Bs, (r * 128 + h * 64 + i * 8) ^ swz);
  }
  __syncthreads();
  f32x4 acc[4][4] = {};
  mfma128(As, Bs, acc, wm, wn, l);
  // epilogue: gather per-node terms, relu, atomic scatter
#pragma unroll
  for (int mi = 0; mi < 4; ++mi)
#pragma unroll
    for (int rr = 0; rr < 4; ++rr) {
      int m = wm * 64 + mi * 16 + (l >> 4) * 4 + rr;
      int e = e0 + m;
      int d = dstI[e], s = srcI[e];
      const unsigned short* xa = Xad + (size_t)d * DIM;
      const unsigned short* xb = Xb + (size_t)s * DIM;
      float* ag = agg + (size_t)d * DIM;
#pragma unroll
      for (int ni = 0; ni < 4; ++ni) {
        int col = wn * 64 + ni * 16 + (l & 15);
        float v = acc[mi][ni][rr] + bf2f(xa[col]) + bf2f(xb[col]);
        v = fmaxf(v, 0.0f);
        unsafeAtomicAdd(ag + col, v);
      }
    }
}

// ---------------- node: out = relu( agg@W2b^T + Yx ) ----------------
__global__ __launch_bounds__(256, 2) void node_kernel(
    const float* __restrict__ agg, const float* __restrict__ W2,
    const unsigned short* __restrict__ Yx, float* __restrict__ out) {
  __shared__ __align__(16) unsigned short As[128 * 128];
  __shared__ __align__(16) unsigned short Bs[128 * 128];
  const int t = threadIdx.x, l = t & 63, w = t >> 6, wm = w >> 1, wn = w & 1;
  const int n0 = blockIdx.x * 128, r = t >> 1, h = t & 1;
  const int swz = (r & 7) << 3;
  {
    int n = n0 + r; if (n >= NNODES) n = NNODES - 1;
    const float* rowp = agg + (size_t)n * DIM + h * 64;
#pragma unroll
    for (int i = 0; i < 8; ++i) cvt8(rowp + i * 8, As, (r * 128 + h * 64 + i * 8) ^ swz);
  }
  {
    const float* bp = W2 + (size_t)r * IN2 + 128 + h * 64;   // agg segment of W2
#pragma unroll
    for (int i = 0; i < 8; ++i) cvt8(bp + i * 8, Bs, (r * 128 + h * 64 + i * 8) ^ swz);
  }
  __syncthreads();
  f32x4 acc[4][4] = {};
  mfma128(As, Bs, acc, wm, wn, l);
#pragma unroll
  for (int mi = 0; mi < 4; ++mi)
#pragma unroll
    for (int rr = 0; rr < 4; ++rr) {
      int m = wm * 64 + mi * 16 + (l >> 4) * 4 + rr;
      int n = n0 + m;
      if (n < NNODES) {
        float* orow = out + (size_t)n * DIM;
#pragma unroll
        for (int ni = 0; ni < 4; ++ni) {
          int col = wn * 64 + ni * 16 + (l & 15);
          float v = acc[mi][ni][rr] + bf2f(Yx[(size_t)n * DIM + col]);
          orow[col] = fmaxf(v, 0.0f);
        }
      }
    }
}

// ================= legacy fallback (round-0, used only if ws too small) =================
__global__ __launch_bounds__(256, 2) void legacy_edge_kernel(
    const float* __restrict__ x, const int* __restrict__ srcI, const int* __restrict__ dstI,
    const float* __restrict__ ea, const float* __restrict__ u, const int* __restrict__ batch,
    const float* __restrict__ W1, const float* __restrict__ b1, float* __restrict__ agg) {
  __shared__ __align__(16) unsigned short As[128 * 128];
  __shared__ __align__(16) unsigned short Bs[128 * 128];
  const int t = threadIdx.x, l = t & 63, w = t >> 6, wm = w >> 1, wn = w & 1;
  const int e0 = blockIdx.x * 128, r = t >> 1, h = t & 1;
  const int swz = (r & 7) << 3;
  f32x4 acc[4][4] = {};
#pragma unroll
  for (int c = 0; c < 4; ++c) {
    __syncthreads();
    const float* rowp;
    if (c == 0)      rowp = x + (size_t)dstI[e0 + r] * DIM;
    else if (c == 1) rowp = x + (size_t)srcI[e0 + r] * DIM;
    else if (c == 2) rowp = ea + (size_t)(e0 + r) * DIM;
    else             rowp = u + (size_t)batch[dstI[e0 + r]] * DIM;
    rowp += h * 64;
#pragma unroll
    for (int i = 0; i < 8; ++i) cvt8(rowp + i * 8, As, (r * 128 + h * 64 + i * 8) ^ swz);
    const float* bp = W1 + (size_t)r * IN1 + c * 128 + h * 64;
#pragma unroll
    for (int i = 0; i < 8; ++i) cvt8(bp + i * 8, Bs, (r * 128 + h * 64 + i * 8) ^ swz);
    __syncthreads();
    mfma128(As, Bs, acc, wm, wn, l);
  }
#pragma unroll
  for (int mi = 0; mi < 4; ++mi)
#pragma unroll
    for (int rr = 0; rr < 4; ++rr) {
      int m = wm * 64 + mi * 16 + (l >> 4) * 4 + rr;
      int d = dstI[e0 + m];
      float* aggrow = agg + (size_t)d * DIM;
#pragma unroll
      for (int ni = 0; ni < 4; ++ni) {
        int col = wn * 64 + ni * 16 + (l & 15);
        float v = acc[mi][ni][rr] + b1[col];
        unsafeAtomicAdd(aggrow + col, fmaxf(v, 0.0f));
      }
    }
}

__global__ __launch_bounds__(256, 2) void legacy_node_kernel(
    const float* __restrict__ x, const float* __restrict__ agg, const float* __restrict__ u,
    const int* __restrict__ batch, const float* __restrict__ W2, const float* __restrict__ b2,
    float* __restrict__ out) {
  __shared__ __align__(16) unsigned short As[128 * 128];
  __shared__ __align__(16) unsigned short Bs[128 * 128];
  const int t = threadIdx.x, l = t & 63, w = t >> 6, wm = w >> 1, wn = w & 1;
  const int n0 = blockIdx.x * 128, r = t >> 1, h = t & 1;
  const int swz = (r & 7) << 3;
  f32x4 acc[4][4] = {};
#pragma unroll
  for (int c = 0; c < 3; ++c) {
    __syncthreads();
    int n = n0 + r; if (n >= NNODES) n = NNODES - 1;
    const float* rowp;
    if (c == 0)      rowp = x + (size_t)n * DIM;
    else if (c == 1) rowp = agg + (size_t)n * DIM;
    else             rowp = u + (size_t)batch[n] * DIM;
    rowp += h * 64;
#pragma unroll
    for (int i = 0; i < 8; ++i) cvt8(rowp + i * 8, As, (r * 128 + h * 64 + i * 8) ^ swz);
    const float* bp = W2 + (size_t)r * IN2 + c * 128 + h * 64;
#pragma unroll
    for (int i = 0; i < 8; ++i) cvt8(bp + i * 8, Bs, (r * 128 + h * 64 + i * 8) ^ swz);
    __syncthreads();
    mfma128(As, Bs, acc, wm, wn, l);
  }
#pragma unroll
  for (int mi = 0; mi < 4; ++mi)
#pragma unroll
    for (int rr = 0; rr < 4; ++rr) {
      int m = wm * 64 + mi * 16 + (l >> 4) * 4 + rr;
      int n = n0 + m;
      if (n < NNODES) {
        float* orow = out + (size_t)n * DIM;
#pragma unroll
        for (int ni = 0; ni < 4; ++ni) {
          int col = wn * 64 + ni * 16 + (l & 15);
          orow[col] = fmaxf(acc[mi][ni][rr] + b2[col], 0.0f);
        }
      }
    }
}

extern "C" void kernel_launch(void* const* d_in, const int* in_sizes, int n_in,
                              void* d_out, int out_size, void* d_ws, size_t ws_size,
                              hipStream_t stream) {
  const float* x   = (const float*)d_in[0];
  const int* ei    = (const int*)d_in[1];
  const float* ea  = (const float*)d_in[2];
  const float* u   = (const float*)d_in[3];
  const int* batch = (const int*)d_in[4];
  const float* W1  = (const float*)d_in[5];
  const float* b1  = (const float*)d_in[6];
  const float* W2  = (const float*)d_in[7];
  const float* b2  = (const float*)d_in[8];
  float* out = (float*)d_out;
  const int* srcI = ei;
  const int* dstI = ei + NEDGES;

  const size_t XAD_B = (size_t)NNODES * DIM * 2;   // bf16
  const size_t U_B   = (size_t)64 * DIM * 4;       // f32
  const size_t need  = 3 * XAD_B + 2 * U_B;        // Xad, Xb, Yx, Ud, Uc  (~38.5 MB)

  if (ws_size >= need) {
    char* p = (char*)d_ws;
    unsigned short* Xad = (unsigned short*)p; p += XAD_B;
    unsigned short* Xb  = (unsigned short*)p; p += XAD_B;
    unsigned short* Yx  = (unsigned short*)p; p += XAD_B;
    float* Ud = (float*)p; p += U_B;
    float* Uc = (float*)p;
    float* agg = out;  // aggregate lives in d_out; node_kernel reads/writes own rows only
    hipMemsetAsync(agg, 0, (size_t)NNODES * DIM * sizeof(float), stream);
    p0_kernel<<<64, 128, 0, stream>>>(u, W1, b1, W2, b2, Ud, Uc);
    p1_kernel<<<(NNODES + 127) / 128, 256, 0, stream>>>(x, batch, W1, W2, Ud, Uc, Xad, Xb, Yx);
    edge_kernel<<<NEDGES / 128, 256, 0, stream>>>(ea, srcI, dstI, W1, Xad, Xb, agg);
    node_kernel<<<(NNODES + 127) / 128, 256, 0, stream>>>(agg, W2, Yx, out);
  } else {
    float* agg = (ws_size >= (size_t)NNODES * DIM * 4) ? (float*)d_ws : out;
    hipMemsetAsync(agg, 0, (size_t)NNODES * DIM * sizeof(float), stream);
    legacy_edge_kernel<<<NEDGES / 128, 256, 0, stream>>>(x, srcI, dstI, ea, u, batch, W1, b1, agg);
    legacy_node_kernel<<<(NNODES + 127) / 128, 256, 0, stream>>>(x, agg, u, batch, W2, b2, out);
  }
}

// Round 3
// 477.789 us; speedup vs baseline: 1.3299x; 1.1896x over previous
//
#include <hip/hip_runtime.h>
#include <stdint.h>

#define NNODES 50000
#define NEDGES 800000
#define DIM 128
#define IN1 512
#define IN2 384

typedef __attribute__((ext_vector_type(8))) short bf16x8;
typedef __attribute__((ext_vector_type(8))) unsigned short u16x8;
typedef __attribute__((ext_vector_type(4))) float f32x4;

__device__ __forceinline__ unsigned short f2bf(float f) {
  union { float f; uint32_t u; } v; v.f = f;
  return (unsigned short)((v.u + 0x7FFFu + ((v.u >> 16) & 1u)) >> 16);
}
__device__ __forceinline__ float bf2f(unsigned short u) {
  union { uint32_t u; float f; } v; v.u = ((uint32_t)u) << 16;
  return v.f;
}

__device__ __forceinline__ void cvt8(const float* __restrict__ p, unsigned short* dst, int sidx) {
  float4 f0 = *(const float4*)(p);
  float4 f1 = *(const float4*)(p + 4);
  u16x8 o;
  o[0] = f2bf(f0.x); o[1] = f2bf(f0.y); o[2] = f2bf(f0.z); o[3] = f2bf(f0.w);
  o[4] = f2bf(f1.x); o[5] = f2bf(f1.y); o[6] = f2bf(f1.z); o[7] = f2bf(f1.w);
  *(u16x8*)(dst + sidx) = o;
}

// 128x128x128 macro-tile, 4 waves as 2x2 of 64x64
__device__ __forceinline__ void mfma128(const unsigned short* As, const unsigned short* Bs,
                                        f32x4 acc[4][4], int wm, int wn, int l) {
#pragma unroll
  for (int kk = 0; kk < 4; ++kk) {
    bf16x8 a[4], b[4];
#pragma unroll
    for (int mi = 0; mi < 4; ++mi) {
      int row = wm * 64 + mi * 16 + (l & 15);
      int idx = (row * 128 + kk * 32 + (l >> 4) * 8) ^ ((row & 7) << 3);
      a[mi] = *(const bf16x8*)(As + idx);
    }
#pragma unroll
    for (int ni = 0; ni < 4; ++ni) {
      int nrow = wn * 64 + ni * 16 + (l & 15);
      int idx = (nrow * 128 + kk * 32 + (l >> 4) * 8) ^ ((nrow & 7) << 3);
      b[ni] = *(const bf16x8*)(Bs + idx);
    }
#pragma unroll
    for (int mi = 0; mi < 4; ++mi)
#pragma unroll
      for (int ni = 0; ni < 4; ++ni)
        acc[mi][ni] = __builtin_amdgcn_mfma_f32_16x16x32_bf16(a[mi], b[ni], acc[mi][ni], 0, 0, 0);
  }
}

// ---------------- P0: Ud = u@W1d^T + b1 ; Uc = u@W2c^T + b2 ----------------
__global__ void p0_kernel(const float* __restrict__ u,
                          const float* __restrict__ W1, const float* __restrict__ b1,
                          const float* __restrict__ W2, const float* __restrict__ b2,
                          float* __restrict__ Ud, float* __restrict__ Uc) {
  int g = blockIdx.x, c = threadIdx.x;
  const float* ur = u + (size_t)g * DIM;
  const float* w1 = W1 + (size_t)c * IN1 + 384;
  const float* w2 = W2 + (size_t)c * IN2 + 256;
  float s1 = b1[c], s2 = b2[c];
  for (int k = 0; k < DIM; ++k) { float uv = ur[k]; s1 += uv * w1[k]; s2 += uv * w2[k]; }
  Ud[g * DIM + c] = s1;
  Uc[g * DIM + c] = s2;
}

// ---------------- P1: Xad/Xb/Yx per-node precompute ----------------
__global__ __launch_bounds__(256, 2) void p1_kernel(
    const float* __restrict__ x, const int* __restrict__ batch,
    const float* __restrict__ W1, const float* __restrict__ W2,
    const float* __restrict__ Ud, const float* __restrict__ Uc,
    unsigned short* __restrict__ Xad, unsigned short* __restrict__ Xb,
    unsigned short* __restrict__ Yx) {
  __shared__ __align__(16) unsigned short As[128 * 128];
  __shared__ __align__(16) unsigned short Bs[128 * 128];
  const int t = threadIdx.x, l = t & 63, w = t >> 6, wm = w >> 1, wn = w & 1;
  const int n0 = blockIdx.x * 128, r = t >> 1, h = t & 1;
  const int swz = (r & 7) << 3;
  {
    int n = n0 + r; if (n >= NNODES) n = NNODES - 1;
    const float* rowp = x + (size_t)n * DIM + h * 64;
#pragma unroll
    for (int i = 0; i < 8; ++i) cvt8(rowp + i * 8, As, (r * 128 + h * 64 + i * 8) ^ swz);
  }
#pragma unroll
  for (int p = 0; p < 3; ++p) {
    __syncthreads();
    const float* bp = (p == 0) ? (W1 + (size_t)r * IN1)
                    : (p == 1) ? (W1 + (size_t)r * IN1 + 128)
                               : (W2 + (size_t)r * IN2);
    bp += h * 64;
#pragma unroll
    for (int i = 0; i < 8; ++i) cvt8(bp + i * 8, Bs, (r * 128 + h * 64 + i * 8) ^ swz);
    __syncthreads();
    f32x4 acc[4][4] = {};
    mfma128(As, Bs, acc, wm, wn, l);
#pragma unroll
    for (int mi = 0; mi < 4; ++mi)
#pragma unroll
      for (int rr = 0; rr < 4; ++rr) {
        int m = wm * 64 + mi * 16 + (l >> 4) * 4 + rr;
        int n = n0 + m;
        if (n < NNODES) {
          int g = batch[n];
#pragma unroll
          for (int ni = 0; ni < 4; ++ni) {
            int col = wn * 64 + ni * 16 + (l & 15);
            float v = acc[mi][ni][rr];
            if (p == 0)      Xad[(size_t)n * DIM + col] = f2bf(v + Ud[g * DIM + col]);
            else if (p == 1) Xb [(size_t)n * DIM + col] = f2bf(v);
            else             Yx [(size_t)n * DIM + col] = f2bf(v + Uc[g * DIM + col]);
          }
        }
      }
  }
}

// ---------------- counting sort by dst ----------------
__global__ void hist_kernel(const int* __restrict__ dstI, int* __restrict__ count) {
  int e = blockIdx.x * 256 + threadIdx.x;
  if (e < NEDGES) atomicAdd(&count[dstI[e]], 1);
}

__global__ void scan_kernel(const int* __restrict__ count, int* __restrict__ rowptr) {
  __shared__ int sums[1024];
  const int CH = 49;                       // 1024*49 = 50176 >= 50000
  int tid = threadIdx.x;
  int base = tid * CH;
  int s = 0;
  for (int i = 0; i < CH; ++i) {
    int idx = base + i;
    s += (idx < NNODES) ? count[idx] : 0;
  }
  sums[tid] = s;
  __syncthreads();
  for (int off = 1; off < 1024; off <<= 1) {
    int v = (tid >= off) ? sums[tid - off] : 0;
    __syncthreads();
    sums[tid] += v;
    __syncthreads();
  }
  int run = (tid > 0) ? sums[tid - 1] : 0;
  for (int i = 0; i < CH; ++i) {
    int idx = base + i;
    if (idx < NNODES) { rowptr[idx] = run; run += count[idx]; }
  }
}

__global__ void scatter_kernel(const int* __restrict__ srcI, const int* __restrict__ dstI,
                               const int* __restrict__ rowptr, int* __restrict__ cursor,
                               int* __restrict__ order, int* __restrict__ dstS,
                               int* __restrict__ srcS) {
  int e = blockIdx.x * 256 + threadIdx.x;
  if (e < NEDGES) {
    int d = dstI[e];
    int pos = rowptr[d] + atomicAdd(&cursor[d], 1);
    order[pos] = e;
    dstS[pos] = d;
    srcS[pos] = srcI[e];
  }
}

// ---------------- edge (sorted): acc = ea[order]@W1c^T ; msg = relu(acc+Xad[dst]+Xb[src])
//                  LDS segmented sum over sorted dst, one atomic per segment ----------------
__global__ __launch_bounds__(512, 4) void edge2_kernel(
    const float* __restrict__ ea, const int* __restrict__ order,
    const int* __restrict__ dstS, const int* __restrict__ srcS,
    const float* __restrict__ W1,
    const unsigned short* __restrict__ Xad, const unsigned short* __restrict__ Xb,
    float* __restrict__ agg) {
  __shared__ __align__(16) unsigned short smem[2 * 128 * 128];   // 64 KB: As|Bs, later Ms(f32)
  __shared__ int dlds[128];
  unsigned short* As = smem;
  unsigned short* Bs = smem + 128 * 128;
  float* Ms = (float*)smem;

  const int t = threadIdx.x, l = t & 63, w = t >> 6;
  const int wm = w >> 2, wn = w & 3;       // 2x4 waves, 64x32 tiles
  const int p0 = blockIdx.x * 128;
  const int r = t >> 2, q = t & 3;         // staging: row r, quarter q (32 floats)
  const int swz = (r & 7) << 3;

  if (t < 128) dlds[t] = dstS[p0 + t];
  {
    int e = order[p0 + r];
    const float* rowp = ea + (size_t)e * DIM + q * 32;
#pragma unroll
    for (int i = 0; i < 4; ++i) cvt8(rowp + i * 8, As, (r * 128 + q * 32 + i * 8) ^ swz);
  }
  {
    const float* bp = W1 + (size_t)r * IN1 + 256 + q * 32;   // W1c segment, L2-hot
#pragma unroll
    for (int i = 0; i < 4; ++i) cvt8(bp + i * 8, Bs, (r * 128 + q * 32 + i * 8) ^ swz);
  }
  __syncthreads();

  f32x4 acc[4][2] = {};
#pragma unroll
  for (int kk = 0; kk < 4; ++kk) {
    bf16x8 a[4], b[2];
#pragma unroll
    for (int mi = 0; mi < 4; ++mi) {
      int row = wm * 64 + mi * 16 + (l & 15);
      int idx = (row * 128 + kk * 32 + (l >> 4) * 8) ^ ((row & 7) << 3);
      a[mi] = *(const bf16x8*)(As + idx);
    }
#pragma unroll
    for (int ni = 0; ni < 2; ++ni) {
      int nrow = wn * 32 + ni * 16 + (l & 15);
      int idx = (nrow * 128 + kk * 32 + (l >> 4) * 8) ^ ((nrow & 7) << 3);
      b[ni] = *(const bf16x8*)(Bs + idx);
    }
#pragma unroll
    for (int mi = 0; mi < 4; ++mi)
#pragma unroll
      for (int ni = 0; ni < 2; ++ni)
        acc[mi][ni] = __builtin_amdgcn_mfma_f32_16x16x32_bf16(a[mi], b[ni], acc[mi][ni], 0, 0, 0);
  }
  __syncthreads();   // all As/Bs reads done; smem becomes Ms

  // write relu'd messages (with gathered per-node terms) into Ms
#pragma unroll
  for (int mi = 0; mi < 4; ++mi)
#pragma unroll
    for (int rr = 0; rr < 4; ++rr) {
      int m = wm * 64 + mi * 16 + (l >> 4) * 4 + rr;
      int d = dlds[m];
      int s = srcS[p0 + m];
      const unsigned short* xa = Xad + (size_t)d * DIM;
      const unsigned short* xb = Xb + (size_t)s * DIM;
#pragma unroll
      for (int ni = 0; ni < 2; ++ni) {
        int col = wn * 32 + ni * 16 + (l & 15);
        float v = acc[mi][ni][rr] + bf2f(xa[col]) + bf2f(xb[col]);
        Ms[m * 128 + col] = fmaxf(v, 0.0f);
      }
    }
  __syncthreads();

  // segmented sum: thread owns (col, 32-row strip); one atomic per dst-run
  {
    int col = t & 127, row0 = (t >> 7) * 32;
    float sum = 0.0f;
    int curd = -1;
    for (int i = 0; i < 32; ++i) {
      int rowi = row0 + i;
      int d = dlds[rowi];
      float v = Ms[rowi * 128 + col];
      if (d != curd) {
        if (curd >= 0) unsafeAtomicAdd(agg + (size_t)curd * DIM + col, sum);
        curd = d; sum = v;
      } else {
        sum += v;
      }
    }
    if (curd >= 0) unsafeAtomicAdd(agg + (size_t)curd * DIM + col, sum);
  }
}

// ---------------- edge (unsorted fallback, round-2) ----------------
__global__ __launch_bounds__(256, 2) void edge_kernel(
    const float* __restrict__ ea, const int* __restrict__ srcI, const int* __restrict__ dstI,
    const float* __restrict__ W1,
    const unsigned short* __restrict__ Xad, const unsigned short* __restrict__ Xb,
    float* __restrict__ agg) {
  __shared__ __align__(16) unsigned short As[128 * 128];
  __shared__ __align__(16) unsigned short Bs[128 * 128];
  const int t = threadIdx.x, l = t & 63, w = t >> 6, wm = w >> 1, wn = w & 1;
  const int e0 = blockIdx.x * 128, r = t >> 1, h = t & 1;
  const int swz = (r & 7) << 3;
  {
    const float* rowp = ea + (size_t)(e0 + r) * DIM + h * 64;
#pragma unroll
    for (int i = 0; i < 8; ++i) cvt8(rowp + i * 8, As, (r * 128 + h * 64 + i * 8) ^ swz);
  }
  {
    const float* bp = W1 + (size_t)r * IN1 + 256 + h * 64;
#pragma unroll
    for (int i = 0; i < 8; ++i) cvt8(bp + i * 8, Bs, (r * 128 + h * 64 + i * 8) ^ swz);
  }
  __syncthreads();
  f32x4 acc[4][4] = {};
  mfma128(As, Bs, acc, wm, wn, l);
#pragma unroll
  for (int mi = 0; mi < 4; ++mi)
#pragma unroll
    for (int rr = 0; rr < 4; ++rr) {
      int m = wm * 64 + mi * 16 + (l >> 4) * 4 + rr;
      int e = e0 + m;
      int d = dstI[e], s = srcI[e];
      const unsigned short* xa = Xad + (size_t)d * DIM;
      const unsigned short* xb = Xb + (size_t)s * DIM;
      float* ag = agg + (size_t)d * DIM;
#pragma unroll
      for (int ni = 0; ni < 4; ++ni) {
        int col = wn * 64 + ni * 16 + (l & 15);
        float v = acc[mi][ni][rr] + bf2f(xa[col]) + bf2f(xb[col]);
        unsafeAtomicAdd(ag + col, fmaxf(v, 0.0f));
      }
    }
}

// ---------------- node: out = relu( agg@W2b^T + Yx ) ----------------
__global__ __launch_bounds__(256, 2) void node_kernel(
    const float* __restrict__ agg, const float* __restrict__ W2,
    const unsigned short* __restrict__ Yx, float* __restrict__ out) {
  __shared__ __align__(16) unsigned short As[128 * 128];
  __shared__ __align__(16) unsigned short Bs[128 * 128];
  const int t = threadIdx.x, l = t & 63, w = t >> 6, wm = w >> 1, wn = w & 1;
  const int n0 = blockIdx.x * 128, r = t >> 1, h = t & 1;
  const int swz = (r & 7) << 3;
  {
    int n = n0 + r; if (n >= NNODES) n = NNODES - 1;
    const float* rowp = agg + (size_t)n * DIM + h * 64;
#pragma unroll
    for (int i = 0; i < 8; ++i) cvt8(rowp + i * 8, As, (r * 128 + h * 64 + i * 8) ^ swz);
  }
  {
    const float* bp = W2 + (size_t)r * IN2 + 128 + h * 64;
#pragma unroll
    for (int i = 0; i < 8; ++i) cvt8(bp + i * 8, Bs, (r * 128 + h * 64 + i * 8) ^ swz);
  }
  __syncthreads();
  f32x4 acc[4][4] = {};
  mfma128(As, Bs, acc, wm, wn, l);
#pragma unroll
  for (int mi = 0; mi < 4; ++mi)
#pragma unroll
    for (int rr = 0; rr < 4; ++rr) {
      int m = wm * 64 + mi * 16 + (l >> 4) * 4 + rr;
      int n = n0 + m;
      if (n < NNODES) {
        float* orow = out + (size_t)n * DIM;
#pragma unroll
        for (int ni = 0; ni < 4; ++ni) {
          int col = wn * 64 + ni * 16 + (l & 15);
          float v = acc[mi][ni][rr] + bf2f(Yx[(size_t)n * DIM + col]);
          orow[col] = fmaxf(v, 0.0f);
        }
      }
    }
}

extern "C" void kernel_launch(void* const* d_in, const int* in_sizes, int n_in,
                              void* d_out, int out_size, void* d_ws, size_t ws_size,
                              hipStream_t stream) {
  const float* x   = (const float*)d_in[0];
  const int* ei    = (const int*)d_in[1];
  const float* ea  = (const float*)d_in[2];
  const float* u   = (const float*)d_in[3];
  const int* batch = (const int*)d_in[4];
  const float* W1  = (const float*)d_in[5];
  const float* b1  = (const float*)d_in[6];
  const float* W2  = (const float*)d_in[7];
  const float* b2  = (const float*)d_in[8];
  float* out = (float*)d_out;
  const int* srcI = ei;
  const int* dstI = ei + NEDGES;

  const size_t XAD_B = (size_t)NNODES * DIM * 2;        // bf16 12.8 MB
  const size_t U_B   = (size_t)64 * DIM * 4;
  const size_t CNT_B = (size_t)(NNODES + 64) * 4;       // padded
  const size_t EDG_B = (size_t)NEDGES * 4;
  const size_t need_base = 3 * XAD_B + 2 * U_B;                       // ~38.5 MB
  const size_t need_sort = need_base + 3 * CNT_B + 3 * EDG_B;         // ~48.7 MB

  char* p = (char*)d_ws;
  unsigned short* Xad = (unsigned short*)p; p += XAD_B;
  unsigned short* Xb  = (unsigned short*)p; p += XAD_B;
  unsigned short* Yx  = (unsigned short*)p; p += XAD_B;
  float* Ud = (float*)p; p += U_B;
  float* Uc = (float*)p; p += U_B;
  int* count  = (int*)p; p += CNT_B;
  int* rowptr = (int*)p; p += CNT_B;
  int* cursor = (int*)p; p += CNT_B;
  int* order  = (int*)p; p += EDG_B;
  int* dstS   = (int*)p; p += EDG_B;
  int* srcS   = (int*)p;

  float* agg = out;   // node_kernel block reads/writes only its own 128-row slice
  hipMemsetAsync(agg, 0, (size_t)NNODES * DIM * sizeof(float), stream);

  if (ws_size >= need_sort) {
    hipMemsetAsync(count, 0, CNT_B, stream);
    hipMemsetAsync(cursor, 0, CNT_B, stream);
    hist_kernel<<<(NEDGES + 255) / 256, 256, 0, stream>>>(dstI, count);
    scan_kernel<<<1, 1024, 0, stream>>>(count, rowptr);
    scatter_kernel<<<(NEDGES + 255) / 256, 256, 0, stream>>>(srcI, dstI, rowptr, cursor,
                                                             order, dstS, srcS);
    p0_kernel<<<64, 128, 0, stream>>>(u, W1, b1, W2, b2, Ud, Uc);
    p1_kernel<<<(NNODES + 127) / 128, 256, 0, stream>>>(x, batch, W1, W2, Ud, Uc, Xad, Xb, Yx);
    edge2_kernel<<<NEDGES / 128, 512, 0, stream>>>(ea, order, dstS, srcS, W1, Xad, Xb, agg);
    node_kernel<<<(NNODES + 127) / 128, 256, 0, stream>>>(agg, W2, Yx, out);
  } else {
    p0_kernel<<<64, 128, 0, stream>>>(u, W1, b1, W2, b2, Ud, Uc);
    p1_kernel<<<(NNODES + 127) / 128, 256, 0, stream>>>(x, batch, W1, W2, Ud, Uc, Xad, Xb, Yx);
    edge_kernel<<<NEDGES / 128, 256, 0, stream>>>(ea, srcI, dstI, W1, Xad, Xb, agg);
    node_kernel<<<(NNODES + 127) / 128, 256, 0, stream>>>(agg, W2, Yx, out);
  }
}

// Round 4
// 465.624 us; speedup vs baseline: 1.3646x; 1.0261x over previous
//
#include <hip/hip_runtime.h>
#include <stdint.h>

#define NNODES 50000
#define NEDGES 800000
#define DIM 128
#define IN1 512
#define IN2 384

typedef __attribute__((ext_vector_type(8))) short bf16x8;
typedef __attribute__((ext_vector_type(8))) unsigned short u16x8;
typedef __attribute__((ext_vector_type(4))) float f32x4;
typedef __attribute__((ext_vector_type(4))) uint32_t u32x4;

__device__ __forceinline__ unsigned short f2bf(float f) {
  union { float f; uint32_t u; } v; v.f = f;
  return (unsigned short)((v.u + 0x7FFFu + ((v.u >> 16) & 1u)) >> 16);
}
__device__ __forceinline__ float bf2f(unsigned short u) {
  union { uint32_t u; float f; } v; v.u = ((uint32_t)u) << 16;
  return v.f;
}
__device__ __forceinline__ uint32_t cvtpk(float lo, float hi) {
  uint32_t r;
  asm volatile("v_cvt_pk_bf16_f32 %0, %1, %2" : "=v"(r) : "v"(lo), "v"(hi));
  return r;
}

__device__ __forceinline__ void cvt8(const float* __restrict__ p, unsigned short* dst, int sidx) {
  float4 f0 = *(const float4*)(p);
  float4 f1 = *(const float4*)(p + 4);
  u16x8 o;
  o[0] = f2bf(f0.x); o[1] = f2bf(f0.y); o[2] = f2bf(f0.z); o[3] = f2bf(f0.w);
  o[4] = f2bf(f1.x); o[5] = f2bf(f1.y); o[6] = f2bf(f1.z); o[7] = f2bf(f1.w);
  *(u16x8*)(dst + sidx) = o;
}

// 128x128x128 macro-tile, 4 waves as 2x2 of 64x64 (used by p1/node/legacy)
__device__ __forceinline__ void mfma128(const unsigned short* As, const unsigned short* Bs,
                                        f32x4 acc[4][4], int wm, int wn, int l) {
#pragma unroll
  for (int kk = 0; kk < 4; ++kk) {
    bf16x8 a[4], b[4];
#pragma unroll
    for (int mi = 0; mi < 4; ++mi) {
      int row = wm * 64 + mi * 16 + (l & 15);
      int idx = (row * 128 + kk * 32 + (l >> 4) * 8) ^ ((row & 7) << 3);
      a[mi] = *(const bf16x8*)(As + idx);
    }
#pragma unroll
    for (int ni = 0; ni < 4; ++ni) {
      int nrow = wn * 64 + ni * 16 + (l & 15);
      int idx = (nrow * 128 + kk * 32 + (l >> 4) * 8) ^ ((nrow & 7) << 3);
      b[ni] = *(const bf16x8*)(Bs + idx);
    }
#pragma unroll
    for (int mi = 0; mi < 4; ++mi)
#pragma unroll
      for (int ni = 0; ni < 4; ++ni)
        acc[mi][ni] = __builtin_amdgcn_mfma_f32_16x16x32_bf16(a[mi], b[ni], acc[mi][ni], 0, 0, 0);
  }
}

// ---------------- P0: Ud = u@W1d^T + b1 ; Uc = u@W2c^T + b2 ----------------
__global__ void p0_kernel(const float* __restrict__ u,
                          const float* __restrict__ W1, const float* __restrict__ b1,
                          const float* __restrict__ W2, const float* __restrict__ b2,
                          float* __restrict__ Ud, float* __restrict__ Uc) {
  int g = blockIdx.x, c = threadIdx.x;
  const float* ur = u + (size_t)g * DIM;
  const float* w1 = W1 + (size_t)c * IN1 + 384;
  const float* w2 = W2 + (size_t)c * IN2 + 256;
  float s1 = b1[c], s2 = b2[c];
  for (int k = 0; k < DIM; ++k) { float uv = ur[k]; s1 += uv * w1[k]; s2 += uv * w2[k]; }
  Ud[g * DIM + c] = s1;
  Uc[g * DIM + c] = s2;
}

// ---------------- wcvt: W1c (cols 256..383 of W1) -> bf16, pre-swizzled LDS layout ----------
__global__ void wcvt_kernel(const float* __restrict__ W1, unsigned short* __restrict__ W1cs) {
  int t = blockIdx.x * 256 + threadIdx.x;    // 64 blocks x 256 = 16384
  int n = t >> 7, k = t & 127;
  int lin = ((n * 128 + (k & ~7)) ^ ((n & 7) << 3)) | (k & 7);
  W1cs[lin] = f2bf(W1[(size_t)n * IN1 + 256 + k]);
}

// ---------------- P1: Xad/Xb/Yx per-node precompute ----------------
__global__ __launch_bounds__(256, 2) void p1_kernel(
    const float* __restrict__ x, const int* __restrict__ batch,
    const float* __restrict__ W1, const float* __restrict__ W2,
    const float* __restrict__ Ud, const float* __restrict__ Uc,
    unsigned short* __restrict__ Xad, unsigned short* __restrict__ Xb,
    unsigned short* __restrict__ Yx) {
  __shared__ __align__(16) unsigned short As[128 * 128];
  __shared__ __align__(16) unsigned short Bs[128 * 128];
  const int t = threadIdx.x, l = t & 63, w = t >> 6, wm = w >> 1, wn = w & 1;
  const int n0 = blockIdx.x * 128, r = t >> 1, h = t & 1;
  const int swz = (r & 7) << 3;
  {
    int n = n0 + r; if (n >= NNODES) n = NNODES - 1;
    const float* rowp = x + (size_t)n * DIM + h * 64;
#pragma unroll
    for (int i = 0; i < 8; ++i) cvt8(rowp + i * 8, As, (r * 128 + h * 64 + i * 8) ^ swz);
  }
#pragma unroll
  for (int p = 0; p < 3; ++p) {
    __syncthreads();
    const float* bp = (p == 0) ? (W1 + (size_t)r * IN1)
                    : (p == 1) ? (W1 + (size_t)r * IN1 + 128)
                               : (W2 + (size_t)r * IN2);
    bp += h * 64;
#pragma unroll
    for (int i = 0; i < 8; ++i) cvt8(bp + i * 8, Bs, (r * 128 + h * 64 + i * 8) ^ swz);
    __syncthreads();
    f32x4 acc[4][4] = {};
    mfma128(As, Bs, acc, wm, wn, l);
#pragma unroll
    for (int mi = 0; mi < 4; ++mi)
#pragma unroll
      for (int rr = 0; rr < 4; ++rr) {
        int m = wm * 64 + mi * 16 + (l >> 4) * 4 + rr;
        int n = n0 + m;
        if (n < NNODES) {
          int g = batch[n];
#pragma unroll
          for (int ni = 0; ni < 4; ++ni) {
            int col = wn * 64 + ni * 16 + (l & 15);
            float v = acc[mi][ni][rr];
            if (p == 0)      Xad[(size_t)n * DIM + col] = f2bf(v + Ud[g * DIM + col]);
            else if (p == 1) Xb [(size_t)n * DIM + col] = f2bf(v);
            else             Yx [(size_t)n * DIM + col] = f2bf(v + Uc[g * DIM + col]);
          }
        }
      }
  }
}

// ---------------- counting sort by dst ----------------
__global__ void hist_kernel(const int* __restrict__ dstI, int* __restrict__ count) {
  int e = blockIdx.x * 256 + threadIdx.x;
  if (e < NEDGES) atomicAdd(&count[dstI[e]], 1);
}

__global__ void scan_kernel(const int* __restrict__ count, int* __restrict__ rowptr) {
  __shared__ int sums[1024];
  const int CH = 49;
  int tid = threadIdx.x;
  int base = tid * CH;
  int s = 0;
  for (int i = 0; i < CH; ++i) {
    int idx = base + i;
    s += (idx < NNODES) ? count[idx] : 0;
  }
  sums[tid] = s;
  __syncthreads();
  for (int off = 1; off < 1024; off <<= 1) {
    int v = (tid >= off) ? sums[tid - off] : 0;
    __syncthreads();
    sums[tid] += v;
    __syncthreads();
  }
  int run = (tid > 0) ? sums[tid - 1] : 0;
  for (int i = 0; i < CH; ++i) {
    int idx = base + i;
    if (idx < NNODES) { rowptr[idx] = run; run += count[idx]; }
  }
}

// destructive on rowptr; one packed 8B write per edge: (e<<32)|(s<<16)|d
__global__ void scatter_kernel(const int* __restrict__ srcI, const int* __restrict__ dstI,
                               int* __restrict__ rowptr, uint64_t* __restrict__ esd) {
  int e = blockIdx.x * 256 + threadIdx.x;
  if (e < NEDGES) {
    int d = dstI[e], s = srcI[e];
    int pos = atomicAdd(&rowptr[d], 1);
    esd[pos] = ((uint64_t)(uint32_t)e << 32) | ((uint32_t)s << 16) | (uint32_t)d;
  }
}

// ---------------- edge2: 64-edge tiles, sorted; acc = ea@W1c^T;
//   msg = relu(acc + Xad[dst] + Xb[src]); LDS segmented sum, atomics per dst-run ----------------
__global__ __launch_bounds__(512, 6) void edge2_kernel(
    const float* __restrict__ ea, const uint64_t* __restrict__ esd,
    const unsigned short* __restrict__ W1cs,
    const unsigned short* __restrict__ Xad, const unsigned short* __restrict__ Xb,
    float* __restrict__ agg) {
  __shared__ __align__(16) unsigned short smem[24576];   // 48KB: As 16KB | Bs 32KB; Ms(32KB) aliases
  __shared__ int dlds[64];
  __shared__ int slds[64];
  unsigned short* As = smem;
  unsigned short* Bs = smem + 8192;
  float* Ms = (float*)smem;

  const int t = threadIdx.x, l = t & 63, w = t >> 6;
  const int wm = w >> 2, wn = w & 3;        // 2x4 waves, 32x32 output tiles
  // bijective XCD-chunked swizzle (nwg=12500, r=4)
  int bid = blockIdx.x;
  const int nwg = NEDGES / 64, q = nwg >> 3, r8 = nwg & 7;
  int xcd = bid & 7, off = bid >> 3;
  int wg = (xcd < r8) ? xcd * (q + 1) + off : r8 * (q + 1) + (xcd - r8) * q + off;
  const int p0 = wg * 64;
  const int r = t >> 3, o = t & 7;          // staging: row r (0..63), octant o (16 floats)

  // ---- stage B: raw copy of pre-swizzled bf16 W1c (64B/thread) ----
  {
    const u16x8* wsrc = (const u16x8*)W1cs;
    u16x8* bdst = (u16x8*)Bs;
#pragma unroll
    for (int i = 0; i < 4; ++i) bdst[t + i * 512] = wsrc[t + i * 512];
  }
  // ---- dst/src for the 64 rows ----
  if (t < 64) {
    uint64_t v = esd[p0 + t];
    dlds[t] = (int)(v & 0xFFFF);
    slds[t] = (int)((v >> 16) & 0xFFFF);
  }
  // ---- stage A: gather ea rows, cvt_pk fp32->bf16, swizzled ----
  {
    uint64_t v = esd[p0 + r];
    int e = (int)(v >> 32);
    const float* rowp = ea + (size_t)e * DIM + o * 16;
    float4 f0 = *(const float4*)(rowp);
    float4 f1 = *(const float4*)(rowp + 4);
    float4 f2 = *(const float4*)(rowp + 8);
    float4 f3 = *(const float4*)(rowp + 12);
    const int swz = (r & 7) << 3;
    u32x4 g0 = {cvtpk(f0.x, f0.y), cvtpk(f0.z, f0.w), cvtpk(f1.x, f1.y), cvtpk(f1.z, f1.w)};
    u32x4 g1 = {cvtpk(f2.x, f2.y), cvtpk(f2.z, f2.w), cvtpk(f3.x, f3.y), cvtpk(f3.z, f3.w)};
    *(u32x4*)(As + ((r * 128 + o * 16) ^ swz)) = g0;
    *(u32x4*)(As + ((r * 128 + o * 16 + 8) ^ swz)) = g1;
  }
  __syncthreads();

  // ---- MFMA: 64x128 tile, K=128 ----
  f32x4 acc[2][2] = {};
#pragma unroll
  for (int kk = 0; kk < 4; ++kk) {
    bf16x8 a[2], b[2];
#pragma unroll
    for (int mi = 0; mi < 2; ++mi) {
      int row = wm * 32 + mi * 16 + (l & 15);
      int idx = (row * 128 + kk * 32 + (l >> 4) * 8) ^ ((row & 7) << 3);
      a[mi] = *(const bf16x8*)(As + idx);
    }
#pragma unroll
    for (int ni = 0; ni < 2; ++ni) {
      int n = wn * 32 + ni * 16 + (l & 15);
      int idx = (n * 128 + kk * 32 + (l >> 4) * 8) ^ ((n & 7) << 3);
      b[ni] = *(const bf16x8*)(Bs + idx);
    }
#pragma unroll
    for (int mi = 0; mi < 2; ++mi)
#pragma unroll
      for (int ni = 0; ni < 2; ++ni)
        acc[mi][ni] = __builtin_amdgcn_mfma_f32_16x16x32_bf16(a[mi], b[ni], acc[mi][ni], 0, 0, 0);
  }
  __syncthreads();   // As/Bs reads done; smem becomes Ms

  // ---- messages -> Ms (col-swizzled to kill 4-way write conflict) ----
#pragma unroll
  for (int mi = 0; mi < 2; ++mi)
#pragma unroll
    for (int rr = 0; rr < 4; ++rr) {
      int m = wm * 32 + mi * 16 + (l >> 4) * 4 + rr;
      int d = dlds[m], s = slds[m];
      const unsigned short* xa = Xad + (size_t)d * DIM;
      const unsigned short* xb = Xb + (size_t)s * DIM;
      int cs = ((m >> 2) & 3) << 3;
#pragma unroll
      for (int ni = 0; ni < 2; ++ni) {
        int col = wn * 32 + ni * 16 + (l & 15);
        float v = acc[mi][ni][rr] + bf2f(xa[col]) + bf2f(xb[col]);
        Ms[m * 128 + (col ^ cs)] = fmaxf(v, 0.0f);
      }
    }
  __syncthreads();

  // ---- segmented sum: thread owns (col, 16-row strip); one atomic per dst-run ----
  {
    int col = t & 127, row0 = (t >> 7) * 16;
    float sum = 0.0f;
    int curd = -1;
    for (int i = 0; i < 16; ++i) {
      int rowi = row0 + i;
      int d = dlds[rowi];
      float v = Ms[rowi * 128 + (col ^ (((rowi >> 2) & 3) << 3))];
      if (d != curd) {
        if (curd >= 0) unsafeAtomicAdd(agg + (size_t)curd * DIM + col, sum);
        curd = d; sum = v;
      } else {
        sum += v;
      }
    }
    if (curd >= 0) unsafeAtomicAdd(agg + (size_t)curd * DIM + col, sum);
  }
}

// ---------------- edge (unsorted fallback) ----------------
__global__ __launch_bounds__(256, 2) void edge_kernel(
    const float* __restrict__ ea, const int* __restrict__ srcI, const int* __restrict__ dstI,
    const float* __restrict__ W1,
    const unsigned short* __restrict__ Xad, const unsigned short* __restrict__ Xb,
    float* __restrict__ agg) {
  __shared__ __align__(16) unsigned short As[128 * 128];
  __shared__ __align__(16) unsigned short Bs[128 * 128];
  const int t = threadIdx.x, l = t & 63, w = t >> 6, wm = w >> 1, wn = w & 1;
  const int e0 = blockIdx.x * 128, r = t >> 1, h = t & 1;
  const int swz = (r & 7) << 3;
  {
    const float* rowp = ea + (size_t)(e0 + r) * DIM + h * 64;
#pragma unroll
    for (int i = 0; i < 8; ++i) cvt8(rowp + i * 8, As, (r * 128 + h * 64 + i * 8) ^ swz);
  }
  {
    const float* bp = W1 + (size_t)r * IN1 + 256 + h * 64;
#pragma unroll
    for (int i = 0; i < 8; ++i) cvt8(bp + i * 8, Bs, (r * 128 + h * 64 + i * 8) ^ swz);
  }
  __syncthreads();
  f32x4 acc[4][4] = {};
  mfma128(As, Bs, acc, wm, wn, l);
#pragma unroll
  for (int mi = 0; mi < 4; ++mi)
#pragma unroll
    for (int rr = 0; rr < 4; ++rr) {
      int m = wm * 64 + mi * 16 + (l >> 4) * 4 + rr;
      int e = e0 + m;
      int d = dstI[e], s = srcI[e];
      const unsigned short* xa = Xad + (size_t)d * DIM;
      const unsigned short* xb = Xb + (size_t)s * DIM;
      float* ag = agg + (size_t)d * DIM;
#pragma unroll
      for (int ni = 0; ni < 4; ++ni) {
        int col = wn * 64 + ni * 16 + (l & 15);
        float v = acc[mi][ni][rr] + bf2f(xa[col]) + bf2f(xb[col]);
        unsafeAtomicAdd(ag + col, fmaxf(v, 0.0f));
      }
    }
}

// ---------------- node: out = relu( agg@W2b^T + Yx ) ----------------
__global__ __launch_bounds__(256, 2) void node_kernel(
    const float* __restrict__ agg, const float* __restrict__ W2,
    const unsigned short* __restrict__ Yx, float* __restrict__ out) {
  __shared__ __align__(16) unsigned short As[128 * 128];
  __shared__ __align__(16) unsigned short Bs[128 * 128];
  const int t = threadIdx.x, l = t & 63, w = t >> 6, wm = w >> 1, wn = w & 1;
  const int n0 = blockIdx.x * 128, r = t >> 1, h = t & 1;
  const int swz = (r & 7) << 3;
  {
    int n = n0 + r; if (n >= NNODES) n = NNODES - 1;
    const float* rowp = agg + (size_t)n * DIM + h * 64;
#pragma unroll
    for (int i = 0; i < 8; ++i) cvt8(rowp + i * 8, As, (r * 128 + h * 64 + i * 8) ^ swz);
  }
  {
    const float* bp = W2 + (size_t)r * IN2 + 128 + h * 64;
#pragma unroll
    for (int i = 0; i < 8; ++i) cvt8(bp + i * 8, Bs, (r * 128 + h * 64 + i * 8) ^ swz);
  }
  __syncthreads();
  f32x4 acc[4][4] = {};
  mfma128(As, Bs, acc, wm, wn, l);
#pragma unroll
  for (int mi = 0; mi < 4; ++mi)
#pragma unroll
    for (int rr = 0; rr < 4; ++rr) {
      int m = wm * 64 + mi * 16 + (l >> 4) * 4 + rr;
      int n = n0 + m;
      if (n < NNODES) {
        float* orow = out + (size_t)n * DIM;
#pragma unroll
        for (int ni = 0; ni < 4; ++ni) {
          int col = wn * 64 + ni * 16 + (l & 15);
          float v = acc[mi][ni][rr] + bf2f(Yx[(size_t)n * DIM + col]);
          orow[col] = fmaxf(v, 0.0f);
        }
      }
    }
}

extern "C" void kernel_launch(void* const* d_in, const int* in_sizes, int n_in,
                              void* d_out, int out_size, void* d_ws, size_t ws_size,
                              hipStream_t stream) {
  const float* x   = (const float*)d_in[0];
  const int* ei    = (const int*)d_in[1];
  const float* ea  = (const float*)d_in[2];
  const float* u   = (const float*)d_in[3];
  const int* batch = (const int*)d_in[4];
  const float* W1  = (const float*)d_in[5];
  const float* b1  = (const float*)d_in[6];
  const float* W2  = (const float*)d_in[7];
  const float* b2  = (const float*)d_in[8];
  float* out = (float*)d_out;
  const int* srcI = ei;
  const int* dstI = ei + NEDGES;

  const size_t XAD_B = (size_t)NNODES * DIM * 2;        // 12.8 MB each (bf16)
  const size_t U_B   = (size_t)64 * DIM * 4;
  const size_t ESD_B = (size_t)NEDGES * 8;              // 6.4 MB
  const size_t CNT_B = (size_t)(NNODES + 64) * 4;
  const size_t W1C_B = (size_t)128 * 128 * 2;
  const size_t need_base = 3 * XAD_B + 2 * U_B;
  const size_t need_sort = need_base + ESD_B + 2 * CNT_B + W1C_B;   // ~45.3 MB

  char* p = (char*)d_ws;
  unsigned short* Xad = (unsigned short*)p; p += XAD_B;
  unsigned short* Xb  = (unsigned short*)p; p += XAD_B;
  unsigned short* Yx  = (unsigned short*)p; p += XAD_B;
  float* Ud = (float*)p; p += U_B;
  float* Uc = (float*)p; p += U_B;
  uint64_t* esd = (uint64_t*)p; p += ESD_B;
  int* count  = (int*)p; p += CNT_B;
  int* rowptr = (int*)p; p += CNT_B;
  unsigned short* W1cs = (unsigned short*)p;

  float* agg = out;   // node_kernel block reads/writes only its own 128-row slice
  hipMemsetAsync(agg, 0, (size_t)NNODES * DIM * sizeof(float), stream);

  if (ws_size >= need_sort) {
    hipMemsetAsync(count, 0, CNT_B, stream);
    hist_kernel<<<(NEDGES + 255) / 256, 256, 0, stream>>>(dstI, count);
    scan_kernel<<<1, 1024, 0, stream>>>(count, rowptr);
    scatter_kernel<<<(NEDGES + 255) / 256, 256, 0, stream>>>(srcI, dstI, rowptr, esd);
    p0_kernel<<<64, 128, 0, stream>>>(u, W1, b1, W2, b2, Ud, Uc);
    wcvt_kernel<<<64, 256, 0, stream>>>(W1, W1cs);
    p1_kernel<<<(NNODES + 127) / 128, 256, 0, stream>>>(x, batch, W1, W2, Ud, Uc, Xad, Xb, Yx);
    edge2_kernel<<<NEDGES / 64, 512, 0, stream>>>(ea, esd, W1cs, Xad, Xb, agg);
    node_kernel<<<(NNODES + 127) / 128, 256, 0, stream>>>(agg, W2, Yx, out);
  } else {
    p0_kernel<<<64, 128, 0, stream>>>(u, W1, b1, W2, b2, Ud, Uc);
    p1_kernel<<<(NNODES + 127) / 128, 256, 0, stream>>>(x, batch, W1, W2, Ud, Uc, Xad, Xb, Yx);
    edge_kernel<<<NEDGES / 128, 256, 0, stream>>>(ea, srcI, dstI, W1, Xad, Xb, agg);
    node_kernel<<<(NNODES + 127) / 128, 256, 0, stream>>>(agg, W2, Yx, out);
  }
}

// Round 5
// 309.815 us; speedup vs baseline: 2.0509x; 1.5029x over previous
//
#include <hip/hip_runtime.h>
#include <stdint.h>

#define NNODES 50000
#define NEDGES 800000
#define DIM 128
#define IN1 512
#define IN2 384
#define NSB 196   // ceil(NNODES/256)

typedef __attribute__((ext_vector_type(8))) short bf16x8;
typedef __attribute__((ext_vector_type(8))) unsigned short u16x8;
typedef __attribute__((ext_vector_type(4))) float f32x4;
typedef __attribute__((ext_vector_type(4))) uint32_t u32x4;

__device__ __forceinline__ unsigned short f2bf(float f) {
  union { float f; uint32_t u; } v; v.f = f;
  return (unsigned short)((v.u + 0x7FFFu + ((v.u >> 16) & 1u)) >> 16);
}
__device__ __forceinline__ float bf2f(unsigned short u) {
  union { uint32_t u; float f; } v; v.u = ((uint32_t)u) << 16;
  return v.f;
}
__device__ __forceinline__ uint32_t cvtpk(float lo, float hi) {
  uint32_t r;
  asm volatile("v_cvt_pk_bf16_f32 %0, %1, %2" : "=v"(r) : "v"(lo), "v"(hi));
  return r;
}

__device__ __forceinline__ void cvt8(const float* __restrict__ p, unsigned short* dst, int sidx) {
  float4 f0 = *(const float4*)(p);
  float4 f1 = *(const float4*)(p + 4);
  u16x8 o;
  o[0] = f2bf(f0.x); o[1] = f2bf(f0.y); o[2] = f2bf(f0.z); o[3] = f2bf(f0.w);
  o[4] = f2bf(f1.x); o[5] = f2bf(f1.y); o[6] = f2bf(f1.z); o[7] = f2bf(f1.w);
  *(u16x8*)(dst + sidx) = o;
}

// 128x128x128 macro-tile, 4 waves as 2x2 of 64x64 (p1/node/fallbacks)
__device__ __forceinline__ void mfma128(const unsigned short* As, const unsigned short* Bs,
                                        f32x4 acc[4][4], int wm, int wn, int l) {
#pragma unroll
  for (int kk = 0; kk < 4; ++kk) {
    bf16x8 a[4], b[4];
#pragma unroll
    for (int mi = 0; mi < 4; ++mi) {
      int row = wm * 64 + mi * 16 + (l & 15);
      int idx = (row * 128 + kk * 32 + (l >> 4) * 8) ^ ((row & 7) << 3);
      a[mi] = *(const bf16x8*)(As + idx);
    }
#pragma unroll
    for (int ni = 0; ni < 4; ++ni) {
      int nrow = wn * 64 + ni * 16 + (l & 15);
      int idx = (nrow * 128 + kk * 32 + (l >> 4) * 8) ^ ((nrow & 7) << 3);
      b[ni] = *(const bf16x8*)(Bs + idx);
    }
#pragma unroll
    for (int mi = 0; mi < 4; ++mi)
#pragma unroll
      for (int ni = 0; ni < 4; ++ni)
        acc[mi][ni] = __builtin_amdgcn_mfma_f32_16x16x32_bf16(a[mi], b[ni], acc[mi][ni], 0, 0, 0);
  }
}

// ---------------- P0: Ud = u@W1d^T + b1 ; Uc = u@W2c^T + b2 ----------------
__global__ void p0_kernel(const float* __restrict__ u,
                          const float* __restrict__ W1, const float* __restrict__ b1,
                          const float* __restrict__ W2, const float* __restrict__ b2,
                          float* __restrict__ Ud, float* __restrict__ Uc) {
  int g = blockIdx.x, c = threadIdx.x;
  const float* ur = u + (size_t)g * DIM;
  const float* w1 = W1 + (size_t)c * IN1 + 384;
  const float* w2 = W2 + (size_t)c * IN2 + 256;
  float s1 = b1[c], s2 = b2[c];
  for (int k = 0; k < DIM; ++k) { float uv = ur[k]; s1 += uv * w1[k]; s2 += uv * w2[k]; }
  Ud[g * DIM + c] = s1;
  Uc[g * DIM + c] = s2;
}

// ---------------- wconv: 5 pre-swizzled bf16 weight tiles ----------------
// tile 0: W1[:,0:128]  1: W1[:,128:256]  2: W1[:,256:384]  3: W2[:,0:128]  4: W2[:,128:256]
__global__ void wconv_kernel(const float* __restrict__ W1, const float* __restrict__ W2,
                             unsigned short* __restrict__ Wt) {
  int t = blockIdx.x * 256 + threadIdx.x;   // 320 blocks -> 81920 = 5*16384
  int tile = t >> 14, rem = t & 16383, n = rem >> 7, k = rem & 127;
  float v = (tile < 3) ? W1[(size_t)n * IN1 + tile * 128 + k]
                       : W2[(size_t)n * IN2 + (tile - 3) * 128 + k];
  int lin = ((n * 128 + (k & ~7)) ^ ((n & 7) << 3)) | (k & 7);
  Wt[tile * 16384 + lin] = f2bf(v);
}

// ---------------- P1: Xad/Xb/Yx per-node precompute ----------------
__global__ __launch_bounds__(256, 2) void p1_kernel(
    const float* __restrict__ x, const int* __restrict__ batch,
    const unsigned short* __restrict__ Wt,
    const float* __restrict__ Ud, const float* __restrict__ Uc,
    unsigned short* __restrict__ Xad, unsigned short* __restrict__ Xb,
    unsigned short* __restrict__ Yx) {
  __shared__ __align__(16) unsigned short As[128 * 128];
  __shared__ __align__(16) unsigned short Bs[128 * 128];
  const int t = threadIdx.x, l = t & 63, w = t >> 6, wm = w >> 1, wn = w & 1;
  const int n0 = blockIdx.x * 128, r = t >> 1, h = t & 1;
  const int swz = (r & 7) << 3;
  {
    int n = n0 + r; if (n >= NNODES) n = NNODES - 1;
    const float* rowp = x + (size_t)n * DIM + h * 64;
#pragma unroll
    for (int i = 0; i < 8; ++i) cvt8(rowp + i * 8, As, (r * 128 + h * 64 + i * 8) ^ swz);
  }
#pragma unroll
  for (int p = 0; p < 3; ++p) {
    __syncthreads();
    {
      const u16x8* wsrc = (const u16x8*)(Wt + (size_t)((p == 2) ? 3 : p) * 16384);
      u16x8* bdst = (u16x8*)Bs;
#pragma unroll
      for (int i = 0; i < 8; ++i) bdst[t + i * 256] = wsrc[t + i * 256];
    }
    __syncthreads();
    f32x4 acc[4][4] = {};
    mfma128(As, Bs, acc, wm, wn, l);
#pragma unroll
    for (int mi = 0; mi < 4; ++mi)
#pragma unroll
      for (int rr = 0; rr < 4; ++rr) {
        int m = wm * 64 + mi * 16 + (l >> 4) * 4 + rr;
        int n = n0 + m;
        if (n < NNODES) {
          int g = batch[n];
#pragma unroll
          for (int ni = 0; ni < 4; ++ni) {
            int col = wn * 64 + ni * 16 + (l & 15);
            float v = acc[mi][ni][rr];
            if (p == 0)      Xad[(size_t)n * DIM + col] = f2bf(v + Ud[g * DIM + col]);
            else if (p == 1) Xb [(size_t)n * DIM + col] = f2bf(v);
            else             Yx [(size_t)n * DIM + col] = f2bf(v + Uc[g * DIM + col]);
          }
        }
      }
  }
}

// ---------------- counting sort by dst ----------------
__global__ void hist_kernel(const int* __restrict__ dstI, int* __restrict__ count) {
  int e = blockIdx.x * 256 + threadIdx.x;
  if (e < NEDGES) atomicAdd(&count[dstI[e]], 1);
}

__global__ void scan1_kernel(const int* __restrict__ count, int* __restrict__ bsum) {
  __shared__ int ws[4];
  int i = blockIdx.x * 256 + threadIdx.x;
  int v = (i < NNODES) ? count[i] : 0;
  int l = threadIdx.x & 63;
#pragma unroll
  for (int off = 32; off > 0; off >>= 1) v += __shfl_down(v, off);
  if (l == 0) ws[threadIdx.x >> 6] = v;
  __syncthreads();
  if (threadIdx.x == 0) bsum[blockIdx.x] = ws[0] + ws[1] + ws[2] + ws[3];
}

__global__ void scan2_kernel(const int* __restrict__ bsum, int* __restrict__ bpre) {
  __shared__ int s[256];
  int i = threadIdx.x;
  int v = (i < NSB) ? bsum[i] : 0;
  s[i] = v; __syncthreads();
  for (int off = 1; off < 256; off <<= 1) {
    int u = (i >= off) ? s[i - off] : 0;
    __syncthreads();
    s[i] += u;
    __syncthreads();
  }
  if (i < NSB) bpre[i] = s[i] - v;   // exclusive
}

__global__ void scan3_kernel(const int* __restrict__ count, const int* __restrict__ bpre,
                             int* __restrict__ rowptr) {
  __shared__ int s[256];
  int b = blockIdx.x, i = threadIdx.x, g = b * 256 + i;
  int v = (g < NNODES) ? count[g] : 0;
  s[i] = v; __syncthreads();
  for (int off = 1; off < 256; off <<= 1) {
    int u = (i >= off) ? s[i - off] : 0;
    __syncthreads();
    s[i] += u;
    __syncthreads();
  }
  if (g < NNODES) rowptr[g] = bpre[b] + s[i] - v;  // exclusive global prefix
}

// destructive on rowptr; one packed 8B write per edge: (e<<32)|(s<<16)|d
__global__ void scatter_kernel(const int* __restrict__ srcI, const int* __restrict__ dstI,
                               int* __restrict__ rowptr, uint64_t* __restrict__ esd) {
  int e = blockIdx.x * 256 + threadIdx.x;
  if (e < NEDGES) {
    int d = dstI[e], s = srcI[e];
    int pos = atomicAdd(&rowptr[d], 1);
    esd[pos] = ((uint64_t)(uint32_t)e << 32) | ((uint32_t)s << 16) | (uint32_t)d;
  }
}

// ---------------- edge2: 64-edge sorted tiles ----------------
__global__ __launch_bounds__(512, 6) void edge2_kernel(
    const float* __restrict__ ea, const uint64_t* __restrict__ esd,
    const unsigned short* __restrict__ W1cs,
    const unsigned short* __restrict__ Xad, const unsigned short* __restrict__ Xb,
    float* __restrict__ agg) {
  __shared__ __align__(16) unsigned short smem[24576];   // 48KB
  __shared__ int dlds[64];
  __shared__ int slds[64];
  unsigned short* As = smem;                 // 16KB
  unsigned short* Bs = smem + 8192;          // 32KB
  unsigned short* Xbs = smem;                // post-MFMA alias of As (16KB, 64x128 bf16)
  float* Ms = (float*)(smem + 8192);         // post-MFMA alias of Bs (32KB, 64x128 f32)

  const int t = threadIdx.x, l = t & 63, w = t >> 6;
  const int wm = w >> 2, wn = w & 3;         // 2x4 waves, 32x32 output tiles
  int bid = blockIdx.x;
  const int nwg = NEDGES / 64, q = nwg >> 3, r8 = nwg & 7;
  int xcd = bid & 7, off = bid >> 3;
  int wg = (xcd < r8) ? xcd * (q + 1) + off : r8 * (q + 1) + (xcd - r8) * q + off;
  const int p0 = wg * 64;
  const int r = t >> 3, o = t & 7;           // staging: row r (0..63), octant o

  // ---- stage B: raw copy of pre-swizzled bf16 W1c ----
  {
    const u16x8* wsrc = (const u16x8*)W1cs;
    u16x8* bdst = (u16x8*)Bs;
#pragma unroll
    for (int i = 0; i < 4; ++i) bdst[t + i * 512] = wsrc[t + i * 512];
  }
  if (t < 64) {
    uint64_t v = esd[p0 + t];
    dlds[t] = (int)(v & 0xFFFF);
    slds[t] = (int)((v >> 16) & 0xFFFF);
  }
  // ---- stage A: gather ea rows, cvt_pk, swizzled ----
  {
    uint64_t v = esd[p0 + r];
    int e = (int)(v >> 32);
    const float* rowp = ea + (size_t)e * DIM + o * 16;
    float4 f0 = *(const float4*)(rowp);
    float4 f1 = *(const float4*)(rowp + 4);
    float4 f2 = *(const float4*)(rowp + 8);
    float4 f3 = *(const float4*)(rowp + 12);
    const int swz = (r & 7) << 3;
    u32x4 g0 = {cvtpk(f0.x, f0.y), cvtpk(f0.z, f0.w), cvtpk(f1.x, f1.y), cvtpk(f1.z, f1.w)};
    u32x4 g1 = {cvtpk(f2.x, f2.y), cvtpk(f2.z, f2.w), cvtpk(f3.x, f3.y), cvtpk(f3.z, f3.w)};
    *(u32x4*)(As + ((r * 128 + o * 16) ^ swz)) = g0;
    *(u32x4*)(As + ((r * 128 + o * 16 + 8) ^ swz)) = g1;
  }
  __syncthreads();

  // ---- MFMA: 64x128 tile, K=128 ----
  f32x4 acc[2][2] = {};
#pragma unroll
  for (int kk = 0; kk < 4; ++kk) {
    bf16x8 a[2], b[2];
#pragma unroll
    for (int mi = 0; mi < 2; ++mi) {
      int row = wm * 32 + mi * 16 + (l & 15);
      int idx = (row * 128 + kk * 32 + (l >> 4) * 8) ^ ((row & 7) << 3);
      a[mi] = *(const bf16x8*)(As + idx);
    }
#pragma unroll
    for (int ni = 0; ni < 2; ++ni) {
      int n = wn * 32 + ni * 16 + (l & 15);
      int idx = (n * 128 + kk * 32 + (l >> 4) * 8) ^ ((n & 7) << 3);
      b[ni] = *(const bf16x8*)(Bs + idx);
    }
#pragma unroll
    for (int mi = 0; mi < 2; ++mi)
#pragma unroll
      for (int ni = 0; ni < 2; ++ni)
        acc[mi][ni] = __builtin_amdgcn_mfma_f32_16x16x32_bf16(a[mi], b[ni], acc[mi][ni], 0, 0, 0);
  }
  __syncthreads();   // As/Bs dead; smem becomes Xbs | Ms

  // ---- cooperative stage of Xb[src] rows into LDS (chunk-swizzled) ----
  {
    int sm = slds[r];
    const u16x8* xr = (const u16x8*)(Xb + (size_t)sm * DIM);
    int sw = ((r >> 2) & 3) << 1;            // u16x8-unit swizzle
    u16x8 xv0 = xr[o * 2];
    u16x8 xv1 = xr[o * 2 + 1];
    u16x8* xb8 = (u16x8*)Xbs;
    xb8[r * 16 + ((o * 2) ^ sw)] = xv0;
    xb8[r * 16 + ((o * 2 + 1) ^ sw)] = xv1;
  }
  __syncthreads();

  // ---- epilogue: v = acc + Xad[dst][col] (L1-hot) + Xbs_lds ; relu -> Ms ----
#pragma unroll
  for (int mi = 0; mi < 2; ++mi)
#pragma unroll
    for (int rr = 0; rr < 4; ++rr) {
      int m = wm * 32 + mi * 16 + (l >> 4) * 4 + rr;
      int d = dlds[m];
      const unsigned short* xa = Xad + (size_t)d * DIM;
      int cs = ((m >> 2) & 3) << 3;          // f32-element swizzle for Ms
      int cx = ((m >> 2) & 3) << 4;          // u16-element swizzle for Xbs
#pragma unroll
      for (int ni = 0; ni < 2; ++ni) {
        int col = wn * 32 + ni * 16 + (l & 15);
        float v = acc[mi][ni][rr] + bf2f(xa[col]) + bf2f(Xbs[m * 128 + (col ^ cx)]);
        Ms[m * 128 + (col ^ cs)] = fmaxf(v, 0.0f);
      }
    }
  __syncthreads();

  // ---- segmented sum: thread owns (col, 16-row strip); one atomic per dst-run ----
  {
    int col = t & 127, row0 = (t >> 7) * 16;
    float sum = 0.0f;
    int curd = -1;
    for (int i = 0; i < 16; ++i) {
      int rowi = row0 + i;
      int d = dlds[rowi];
      float v = Ms[rowi * 128 + (col ^ (((rowi >> 2) & 3) << 3))];
      if (d != curd) {
        if (curd >= 0) unsafeAtomicAdd(agg + (size_t)curd * DIM + col, sum);
        curd = d; sum = v;
      } else {
        sum += v;
      }
    }
    if (curd >= 0) unsafeAtomicAdd(agg + (size_t)curd * DIM + col, sum);
  }
}

// ---------------- edge (unsorted fallback) ----------------
__global__ __launch_bounds__(256, 2) void edge_kernel(
    const float* __restrict__ ea, const int* __restrict__ srcI, const int* __restrict__ dstI,
    const unsigned short* __restrict__ W1cs,
    const unsigned short* __restrict__ Xad, const unsigned short* __restrict__ Xb,
    float* __restrict__ agg) {
  __shared__ __align__(16) unsigned short As[128 * 128];
  __shared__ __align__(16) unsigned short Bs[128 * 128];
  const int t = threadIdx.x, l = t & 63, w = t >> 6, wm = w >> 1, wn = w & 1;
  const int e0 = blockIdx.x * 128, r = t >> 1, h = t & 1;
  const int swz = (r & 7) << 3;
  {
    const float* rowp = ea + (size_t)(e0 + r) * DIM + h * 64;
#pragma unroll
    for (int i = 0; i < 8; ++i) cvt8(rowp + i * 8, As, (r * 128 + h * 64 + i * 8) ^ swz);
  }
  {
    const u16x8* wsrc = (const u16x8*)W1cs;
    u16x8* bdst = (u16x8*)Bs;
#pragma unroll
    for (int i = 0; i < 8; ++i) bdst[t + i * 256] = wsrc[t + i * 256];
  }
  __syncthreads();
  f32x4 acc[4][4] = {};
  mfma128(As, Bs, acc, wm, wn, l);
#pragma unroll
  for (int mi = 0; mi < 4; ++mi)
#pragma unroll
    for (int rr = 0; rr < 4; ++rr) {
      int m = wm * 64 + mi * 16 + (l >> 4) * 4 + rr;
      int e = e0 + m;
      int d = dstI[e], s = srcI[e];
      const unsigned short* xa = Xad + (size_t)d * DIM;
      const unsigned short* xb = Xb + (size_t)s * DIM;
      float* ag = agg + (size_t)d * DIM;
#pragma unroll
      for (int ni = 0; ni < 4; ++ni) {
        int col = wn * 64 + ni * 16 + (l & 15);
        float v = acc[mi][ni][rr] + bf2f(xa[col]) + bf2f(xb[col]);
        unsafeAtomicAdd(ag + col, fmaxf(v, 0.0f));
      }
    }
}

// ---------------- node: out = relu( agg@W2b^T + Yx ) ----------------
__global__ __launch_bounds__(256, 2) void node_kernel(
    const float* __restrict__ agg, const unsigned short* __restrict__ Wt,
    const unsigned short* __restrict__ Yx, float* __restrict__ out) {
  __shared__ __align__(16) unsigned short As[128 * 128];
  __shared__ __align__(16) unsigned short Bs[128 * 128];
  const int t = threadIdx.x, l = t & 63, w = t >> 6, wm = w >> 1, wn = w & 1;
  const int n0 = blockIdx.x * 128, r = t >> 1, h = t & 1;
  const int swz = (r & 7) << 3;
  {
    int n = n0 + r; if (n >= NNODES) n = NNODES - 1;
    const float* rowp = agg + (size_t)n * DIM + h * 64;
#pragma unroll
    for (int i = 0; i < 8; ++i) cvt8(rowp + i * 8, As, (r * 128 + h * 64 + i * 8) ^ swz);
  }
  {
    const u16x8* wsrc = (const u16x8*)(Wt + (size_t)4 * 16384);   // W2 seg1
    u16x8* bdst = (u16x8*)Bs;
#pragma unroll
    for (int i = 0; i < 8; ++i) bdst[t + i * 256] = wsrc[t + i * 256];
  }
  __syncthreads();
  f32x4 acc[4][4] = {};
  mfma128(As, Bs, acc, wm, wn, l);
#pragma unroll
  for (int mi = 0; mi < 4; ++mi)
#pragma unroll
    for (int rr = 0; rr < 4; ++rr) {
      int m = wm * 64 + mi * 16 + (l >> 4) * 4 + rr;
      int n = n0 + m;
      if (n < NNODES) {
        float* orow = out + (size_t)n * DIM;
#pragma unroll
        for (int ni = 0; ni < 4; ++ni) {
          int col = wn * 64 + ni * 16 + (l & 15);
          float v = acc[mi][ni][rr] + bf2f(Yx[(size_t)n * DIM + col]);
          orow[col] = fmaxf(v, 0.0f);
        }
      }
    }
}

extern "C" void kernel_launch(void* const* d_in, const int* in_sizes, int n_in,
                              void* d_out, int out_size, void* d_ws, size_t ws_size,
                              hipStream_t stream) {
  const float* x   = (const float*)d_in[0];
  const int* ei    = (const int*)d_in[1];
  const float* ea  = (const float*)d_in[2];
  const float* u   = (const float*)d_in[3];
  const int* batch = (const int*)d_in[4];
  const float* W1  = (const float*)d_in[5];
  const float* b1  = (const float*)d_in[6];
  const float* W2  = (const float*)d_in[7];
  const float* b2  = (const float*)d_in[8];
  float* out = (float*)d_out;
  const int* srcI = ei;
  const int* dstI = ei + NEDGES;

  const size_t XAD_B = (size_t)NNODES * DIM * 2;        // 12.8 MB each (bf16)
  const size_t U_B   = (size_t)64 * DIM * 4;
  const size_t WT_B  = (size_t)5 * 16384 * 2;           // 160 KB
  const size_t ESD_B = (size_t)NEDGES * 8;              // 6.4 MB
  const size_t CNT_B = (size_t)(NNODES + 64) * 4;
  const size_t BS_B  = 4096;
  const size_t need_base = 3 * XAD_B + 2 * U_B + WT_B;
  const size_t need_sort = need_base + ESD_B + 2 * CNT_B + 2 * BS_B;

  char* p = (char*)d_ws;
  unsigned short* Xad = (unsigned short*)p; p += XAD_B;
  unsigned short* Xb  = (unsigned short*)p; p += XAD_B;
  unsigned short* Yx  = (unsigned short*)p; p += XAD_B;
  float* Ud = (float*)p; p += U_B;
  float* Uc = (float*)p; p += U_B;
  unsigned short* Wt = (unsigned short*)p; p += WT_B;
  uint64_t* esd = (uint64_t*)p; p += ESD_B;
  int* count  = (int*)p; p += CNT_B;
  int* rowptr = (int*)p; p += CNT_B;
  int* bsum = (int*)p; p += BS_B;
  int* bpre = (int*)p;

  float* agg = out;   // node_kernel block reads/writes only its own 128-row slice

  if (ws_size >= need_sort) {
    hipMemsetAsync(agg, 0, (size_t)NNODES * DIM * sizeof(float), stream);
    hipMemsetAsync(count, 0, CNT_B, stream);
    hist_kernel<<<(NEDGES + 255) / 256, 256, 0, stream>>>(dstI, count);
    scan1_kernel<<<NSB, 256, 0, stream>>>(count, bsum);
    scan2_kernel<<<1, 256, 0, stream>>>(bsum, bpre);
    scan3_kernel<<<NSB, 256, 0, stream>>>(count, bpre, rowptr);
    scatter_kernel<<<(NEDGES + 255) / 256, 256, 0, stream>>>(srcI, dstI, rowptr, esd);
    p0_kernel<<<64, 128, 0, stream>>>(u, W1, b1, W2, b2, Ud, Uc);
    wconv_kernel<<<320, 256, 0, stream>>>(W1, W2, Wt);
    p1_kernel<<<(NNODES + 127) / 128, 256, 0, stream>>>(x, batch, Wt, Ud, Uc, Xad, Xb, Yx);
    edge2_kernel<<<NEDGES / 64, 512, 0, stream>>>(ea, esd, Wt + 2 * 16384, Xad, Xb, agg);
    node_kernel<<<(NNODES + 127) / 128, 256, 0, stream>>>(agg, Wt, Yx, out);
  } else if (ws_size >= need_base) {
    hipMemsetAsync(agg, 0, (size_t)NNODES * DIM * sizeof(float), stream);
    p0_kernel<<<64, 128, 0, stream>>>(u, W1, b1, W2, b2, Ud, Uc);
    wconv_kernel<<<320, 256, 0, stream>>>(W1, W2, Wt);
    p1_kernel<<<(NNODES + 127) / 128, 256, 0, stream>>>(x, batch, Wt, Ud, Uc, Xad, Xb, Yx);
    edge_kernel<<<NEDGES / 128, 256, 0, stream>>>(ea, srcI, dstI, Wt + 2 * 16384, Xad, Xb, agg);
    node_kernel<<<(NNODES + 127) / 128, 256, 0, stream>>>(agg, Wt, Yx, out);
  }
}